// Round 1
// baseline (808481.738 us; speedup 1.0000x reference)
//
#include <hip/hip_runtime.h>

#define B_TOT 2048
#define T_LEN 1024
#define HID   512
#define CH    9
#define CONDK 272        // 128 + 128 + 16
#define K1X   (2*CH)     // x part of GRU1 K
#define G3    1536       // 3*HID
#define ROWS  4          // batch rows per workgroup
#define NWG   (B_TOT/ROWS)
#define NTHR  512

// ws layout (floats)
#define SZ_W1T  ((HID + K1X) * G3)   // 530*1536 = 814080
#define SZ_W2T  ((2*HID) * G3)       // 1024*1536 = 1572864
#define SZ_WHT  (CONDK * HID)        // 139264
#define OFF_W1T 0
#define OFF_W2T (OFF_W1T + SZ_W1T)
#define OFF_WHT (OFF_W2T + SZ_W2T)

__global__ void prep_kernel(const float* __restrict__ w_ih1, const float* __restrict__ w_hh1,
                            const float* __restrict__ w_ih2, const float* __restrict__ w_hh2,
                            const float* __restrict__ W_h, float* __restrict__ ws)
{
    int i = blockIdx.x * blockDim.x + threadIdx.x;
    const int total = SZ_W1T + SZ_W2T + SZ_WHT;
    if (i >= total) return;
    if (i < SZ_W1T) {
        int k = i / G3, g = i % G3;
        ws[OFF_W1T + i] = (k < HID) ? w_hh1[g*HID + k] : w_ih1[g*K1X + (k - HID)];
    } else if (i < SZ_W1T + SZ_W2T) {
        int j = i - SZ_W1T;
        int k = j / G3, g = j % G3;
        ws[OFF_W2T + j] = (k < HID) ? w_hh2[g*HID + k] : w_ih2[g*HID + (k - HID)];
    } else {
        int j = i - SZ_W1T - SZ_W2T;
        int k = j / HID, u = j % HID;
        ws[OFF_WHT + j] = W_h[u*CONDK + k];
    }
}

__global__ __launch_bounds__(NTHR, 4)
void note_decoder_kernel(const float* __restrict__ z, const float* __restrict__ se,
                         const float* __restrict__ skel, const float* __restrict__ cond,
                         const float* __restrict__ rnd,
                         const float* __restrict__ b_h,
                         const float* __restrict__ b_ih1, const float* __restrict__ b_hh1,
                         const float* __restrict__ b_ih2, const float* __restrict__ b_hh2,
                         const float* __restrict__ W_out, const float* __restrict__ b_out,
                         const float* __restrict__ ws,
                         float* __restrict__ out)
{
    __shared__ double h1s[ROWS][HID];
    __shared__ double h2s[ROWS][HID];
    __shared__ float  xf[ROWS][2*CH];     // [out(9) | skel(9)] as exact f32
    __shared__ float  wouts[CH][HID];

    const float* __restrict__ W1t = ws + OFF_W1T;
    const float* __restrict__ W2t = ws + OFF_W2T;
    const float* __restrict__ Wht = ws + OFF_WHT;

    const int tid  = threadIdx.x;          // owns hidden unit `tid`
    const int row0 = blockIdx.x * ROWS;

    // stage W_out into LDS (reused every step)
    for (int i = tid; i < CH*HID; i += NTHR) wouts[i / HID][i % HID] = W_out[i];

    // stage zc = [z | skel_encoded | cond] (f64) into h2s scratch
    for (int i = tid; i < ROWS*CONDK; i += NTHR) {
        int b = i / CONDK, k = i % CONDK;
        float v;
        if (k < 128)       v = z[(row0 + b)*128 + k];
        else if (k < 256)  v = se[(row0 + b)*128 + (k - 128)];
        else               v = cond[(row0 + b)*16 + (k - 256)];
        h2s[b][k] = (double)v;
    }
    if (tid < ROWS*CH) xf[tid / CH][tid % CH] = 0.0f;   // out0 = 0
    __syncthreads();

    // h1_0 = tanh(zc @ W_h^T + b_h)
    {
        double acc[ROWS];
        #pragma unroll
        for (int b = 0; b < ROWS; ++b) acc[b] = 0.0;
        for (int k = 0; k < CONDK; ++k) {
            double w = (double)Wht[k*HID + tid];
            #pragma unroll
            for (int b = 0; b < ROWS; ++b) acc[b] += h2s[b][k] * w;
        }
        double bh = (double)b_h[tid];
        __syncthreads();   // done reading zc scratch
        #pragma unroll
        for (int b = 0; b < ROWS; ++b) h1s[b][tid] = tanh(acc[b] + bh);
    }
    __syncthreads();

    // hoist biases (constant across steps)
    const double br1 = (double)b_ih1[tid]         + (double)b_hh1[tid];
    const double bz1 = (double)b_ih1[HID + tid]   + (double)b_hh1[HID + tid];
    const double bi1 = (double)b_ih1[2*HID + tid];
    const double bn1 = (double)b_hh1[2*HID + tid];
    const double br2 = (double)b_ih2[tid]         + (double)b_hh2[tid];
    const double bz2 = (double)b_ih2[HID + tid]   + (double)b_hh2[HID + tid];
    const double bi2 = (double)b_ih2[2*HID + tid];
    const double bn2 = (double)b_hh2[2*HID + tid];

    for (int t = 0; t < T_LEN; ++t) {
        // build skel half of x
        if (tid < ROWS*CH) {
            int b = tid / CH, c = tid % CH;
            xf[b][CH + c] = skel[(size_t)(row0 + b)*T_LEN*CH + (size_t)t*CH + c];
        }
        __syncthreads();

        // ---- GRU1: gi = x@w_ih1^T, gh = h1@w_hh1^T ----
        double ar[ROWS], az[ROWS], ai[ROWS], ah[ROWS];
        #pragma unroll
        for (int b = 0; b < ROWS; ++b) { ar[b]=0.0; az[b]=0.0; ai[b]=0.0; ah[b]=0.0; }
        for (int k = 0; k < HID; ++k) {                  // h-part -> r,z,hn
            const float* wr = W1t + (size_t)k*G3;
            double w_r = (double)wr[tid], w_z = (double)wr[HID + tid], w_n = (double)wr[2*HID + tid];
            #pragma unroll
            for (int b = 0; b < ROWS; ++b) {
                double h = h1s[b][k];
                ar[b] += h*w_r; az[b] += h*w_z; ah[b] += h*w_n;
            }
        }
        for (int k = 0; k < K1X; ++k) {                  // x-part -> r,z,in
            const float* wr = W1t + (size_t)(HID + k)*G3;
            double w_r = (double)wr[tid], w_z = (double)wr[HID + tid], w_n = (double)wr[2*HID + tid];
            #pragma unroll
            for (int b = 0; b < ROWS; ++b) {
                double xv = (double)xf[b][k];
                ar[b] += xv*w_r; az[b] += xv*w_z; ai[b] += xv*w_n;
            }
        }
        double h1n[ROWS];
        #pragma unroll
        for (int b = 0; b < ROWS; ++b) {
            double r  = 1.0/(1.0 + exp(-(ar[b] + br1)));
            double zg = 1.0/(1.0 + exp(-(az[b] + bz1)));
            double n  = tanh(ai[b] + bi1 + r*(ah[b] + bn1));
            h1n[b] = (1.0 - zg)*n + zg*h1s[b][tid];
        }
        __syncthreads();   // everyone done reading old h1
        #pragma unroll
        for (int b = 0; b < ROWS; ++b) h1s[b][tid] = h1n[b];
        if (t == 0) {
            #pragma unroll
            for (int b = 0; b < ROWS; ++b) h2s[b][tid] = h1n[b];   // hx[1] = hx[0] at i==0
        }
        __syncthreads();

        // ---- GRU2: input = h1(new), hidden = h2 ----
        #pragma unroll
        for (int b = 0; b < ROWS; ++b) { ar[b]=0.0; az[b]=0.0; ai[b]=0.0; ah[b]=0.0; }
        for (int k = 0; k < HID; ++k) {                  // h2-part -> r,z,hn
            const float* wr = W2t + (size_t)k*G3;
            double w_r = (double)wr[tid], w_z = (double)wr[HID + tid], w_n = (double)wr[2*HID + tid];
            #pragma unroll
            for (int b = 0; b < ROWS; ++b) {
                double h = h2s[b][k];
                ar[b] += h*w_r; az[b] += h*w_z; ah[b] += h*w_n;
            }
        }
        for (int k = 0; k < HID; ++k) {                  // h1-part -> r,z,in
            const float* wr = W2t + (size_t)(HID + k)*G3;
            double w_r = (double)wr[tid], w_z = (double)wr[HID + tid], w_n = (double)wr[2*HID + tid];
            #pragma unroll
            for (int b = 0; b < ROWS; ++b) {
                double h = h1s[b][k];
                ar[b] += h*w_r; az[b] += h*w_z; ai[b] += h*w_n;
            }
        }
        double h2n[ROWS];
        #pragma unroll
        for (int b = 0; b < ROWS; ++b) {
            double r  = 1.0/(1.0 + exp(-(ar[b] + br2)));
            double zg = 1.0/(1.0 + exp(-(az[b] + bz2)));
            double n  = tanh(ai[b] + bi2 + r*(ah[b] + bn2));
            h2n[b] = (1.0 - zg)*n + zg*h2s[b][tid];
        }
        __syncthreads();
        #pragma unroll
        for (int b = 0; b < ROWS; ++b) h2s[b][tid] = h2n[b];
        __syncthreads();

        // ---- note = tanh(h2) @ W_out^T + b_out; Bernoulli sample ----
        {
            const int wv = tid >> 6, ln = tid & 63;
            if (wv < ROWS) {
                double na[CH];
                #pragma unroll
                for (int c = 0; c < CH; ++c) na[c] = 0.0;
                for (int kk = ln; kk < HID; kk += 64) {
                    double th = tanh(h2s[wv][kk]);
                    #pragma unroll
                    for (int c = 0; c < CH; ++c) na[c] += th * (double)wouts[c][kk];
                }
                #pragma unroll
                for (int c = 0; c < CH; ++c) {
                    #pragma unroll
                    for (int off = 32; off; off >>= 1)
                        na[c] += __shfl_xor(na[c], off, 64);
                }
                if (ln < CH) {
                    int c = ln;
                    double note = na[c] + (double)b_out[c];
                    double sg = 1.0/(1.0 + exp(-note));
                    double rv = (double)rnd[(size_t)t*B_TOT*CH + (size_t)(row0 + wv)*CH + c];
                    xf[wv][c] = (sg - rv > 0.0) ? 1.0f : 0.0f;   // feedback bit
                    out[(size_t)(row0 + wv)*T_LEN*CH + (size_t)t*CH + c] = (float)note;
                }
            }
        }
        __syncthreads();
    }
}

extern "C" void kernel_launch(void* const* d_in, const int* in_sizes, int n_in,
                              void* d_out, int out_size, void* d_ws, size_t ws_size,
                              hipStream_t stream)
{
    const float* z     = (const float*)d_in[0];
    const float* se    = (const float*)d_in[1];
    const float* skel  = (const float*)d_in[2];
    const float* cond  = (const float*)d_in[3];
    const float* rnd   = (const float*)d_in[4];
    // d_in[5] = W_h (transposed in prep)
    const float* W_h   = (const float*)d_in[5];
    const float* b_h   = (const float*)d_in[6];
    const float* w_ih1 = (const float*)d_in[7];
    const float* w_hh1 = (const float*)d_in[8];
    const float* b_ih1 = (const float*)d_in[9];
    const float* b_hh1 = (const float*)d_in[10];
    const float* w_ih2 = (const float*)d_in[11];
    const float* w_hh2 = (const float*)d_in[12];
    const float* b_ih2 = (const float*)d_in[13];
    const float* b_hh2 = (const float*)d_in[14];
    const float* W_out = (const float*)d_in[15];
    const float* b_out = (const float*)d_in[16];
    float* ws  = (float*)d_ws;
    float* out = (float*)d_out;

    const int total = SZ_W1T + SZ_W2T + SZ_WHT;
    prep_kernel<<<(total + 255)/256, 256, 0, stream>>>(w_ih1, w_hh1, w_ih2, w_hh2, W_h, ws);
    note_decoder_kernel<<<NWG, NTHR, 0, stream>>>(z, se, skel, cond, rnd, b_h,
                                                  b_ih1, b_hh1, b_ih2, b_hh2,
                                                  W_out, b_out, ws, out);
}

// Round 2
// 192449.280 us; speedup vs baseline: 4.2010x; 4.2010x over previous
//
#include <hip/hip_runtime.h>
#include <math.h>

#define B_TOT 2048
#define T_LEN 1024
#define HID   512
#define CH    9
#define CONDK 272        // 128 + 128 + 16
#define K1X   (2*CH)     // x part of GRU1 K
#define G3    1536       // 3*HID
#define ROWS  8          // batch rows per workgroup
#define NWG   (B_TOT/ROWS)   // 256 = 1 WG per CU
#define NTHR  512

// ws layout (floats), k-major weight panels
#define SZ_W1T  ((HID + K1X) * G3)   // 530*1536
#define SZ_W2T  ((2*HID) * G3)       // 1024*1536
#define SZ_WHT  (CONDK * HID)
#define OFF_W1T 0
#define OFF_W2T (OFF_W1T + SZ_W1T)
#define OFF_WHT (OFF_W2T + SZ_W2T)

__global__ void prep_kernel(const float* __restrict__ w_ih1, const float* __restrict__ w_hh1,
                            const float* __restrict__ w_ih2, const float* __restrict__ w_hh2,
                            const float* __restrict__ W_h, float* __restrict__ ws)
{
    int i = blockIdx.x * blockDim.x + threadIdx.x;
    const int total = SZ_W1T + SZ_W2T + SZ_WHT;
    if (i >= total) return;
    if (i < SZ_W1T) {
        int k = i / G3, g = i % G3;
        ws[OFF_W1T + i] = (k < HID) ? w_hh1[g*HID + k] : w_ih1[g*K1X + (k - HID)];
    } else if (i < SZ_W1T + SZ_W2T) {
        int j = i - SZ_W1T;
        int k = j / G3, g = j % G3;
        ws[OFF_W2T + j] = (k < HID) ? w_hh2[g*HID + k] : w_ih2[g*HID + (k - HID)];
    } else {
        int j = i - SZ_W1T - SZ_W2T;
        int k = j / HID, u = j % HID;
        ws[OFF_WHT + j] = W_h[u*CONDK + k];
    }
}

__device__ __forceinline__ float sigmf(float x) { return 1.0f / (1.0f + expf(-x)); }

__global__ __launch_bounds__(NTHR, 2)
void note_decoder_kernel(const float* __restrict__ z, const float* __restrict__ se,
                         const float* __restrict__ skel, const float* __restrict__ cond,
                         const float* __restrict__ rnd,
                         const float* __restrict__ b_h,
                         const float* __restrict__ b_ih1, const float* __restrict__ b_hh1,
                         const float* __restrict__ b_ih2, const float* __restrict__ b_hh2,
                         const float* __restrict__ W_out, const float* __restrict__ b_out,
                         const float* __restrict__ ws,
                         float* __restrict__ out)
{
    // k-major state: h[k][b] so the wave-uniform k reads are LDS broadcasts (2x b128)
    __shared__ float h1s[HID][ROWS];
    __shared__ float h2s[HID][ROWS];
    __shared__ float xf[2*CH][ROWS];      // x = [out(9) | skel(9)], k-major
    __shared__ float wouts[HID][CH];

    const float* __restrict__ W1t = ws + OFF_W1T;
    const float* __restrict__ W2t = ws + OFF_W2T;
    const float* __restrict__ Wht = ws + OFF_WHT;

    const int tid  = threadIdx.x;          // owns hidden unit `tid`
    const int row0 = blockIdx.x * ROWS;

    // stage W_out as [u][c]
    for (int i = tid; i < CH*HID; i += NTHR) {
        int c = i / HID, u = i % HID;
        wouts[u][c] = W_out[i];
    }
    // stage zc = [z | skel_encoded | cond] into h2s scratch, k-major
    for (int i = tid; i < ROWS*CONDK; i += NTHR) {
        int b = i / CONDK, k = i % CONDK;
        float v;
        if (k < 128)       v = z[(row0 + b)*128 + k];
        else if (k < 256)  v = se[(row0 + b)*128 + (k - 128)];
        else               v = cond[(row0 + b)*16 + (k - 256)];
        h2s[k][b] = v;
    }
    if (tid < ROWS*CH) xf[tid % CH][tid / CH] = 0.0f;   // out0 = 0 (xf[c][b])
    __syncthreads();

    // h1_0 = tanh(zc @ W_h^T + b_h)
    {
        float acc[ROWS];
        #pragma unroll
        for (int b = 0; b < ROWS; ++b) acc[b] = 0.0f;
        for (int k = 0; k < CONDK; ++k) {
            float w = Wht[k*HID + tid];
            float4 a0 = *(const float4*)&h2s[k][0];
            float4 a1 = *(const float4*)&h2s[k][4];
            float hv[ROWS] = {a0.x,a0.y,a0.z,a0.w,a1.x,a1.y,a1.z,a1.w};
            #pragma unroll
            for (int b = 0; b < ROWS; ++b) acc[b] = fmaf(hv[b], w, acc[b]);
        }
        float bh = b_h[tid];
        __syncthreads();   // done reading zc scratch
        #pragma unroll
        for (int b = 0; b < ROWS; ++b) acc[b] = tanhf(acc[b] + bh);
        *(float4*)&h1s[tid][0] = make_float4(acc[0],acc[1],acc[2],acc[3]);
        *(float4*)&h1s[tid][4] = make_float4(acc[4],acc[5],acc[6],acc[7]);
    }
    __syncthreads();

    // hoisted biases
    const float br1 = b_ih1[tid]         + b_hh1[tid];
    const float bz1 = b_ih1[HID + tid]   + b_hh1[HID + tid];
    const float bi1 = b_ih1[2*HID + tid];
    const float bn1 = b_hh1[2*HID + tid];
    const float br2 = b_ih2[tid]         + b_hh2[tid];
    const float bz2 = b_ih2[HID + tid]   + b_hh2[HID + tid];
    const float bi2 = b_ih2[2*HID + tid];
    const float bn2 = b_hh2[2*HID + tid];

    const int wv = tid >> 6, ln = tid & 63;

    for (int t = 0; t < T_LEN; ++t) {
        // stage skel half of x (xf[9..17][b]); feedback xf[0..8][b] from prev step
        if (tid < ROWS*CH) {
            int b = tid / CH, c = tid % CH;
            xf[CH + c][b] = skel[((size_t)(row0 + b)*T_LEN + t)*CH + c];
        }
        __syncthreads();

        // ---- GRU1 ----
        float ar[ROWS], az[ROWS], ai[ROWS], ah[ROWS];
        #pragma unroll
        for (int b = 0; b < ROWS; ++b) { ar[b]=0.f; az[b]=0.f; ai[b]=0.f; ah[b]=0.f; }
        #pragma unroll 4
        for (int k = 0; k < HID; ++k) {                  // h-part -> r,z,hn
            const float* wr = W1t + (size_t)k*G3;
            float w_r = wr[tid], w_z = wr[HID + tid], w_n = wr[2*HID + tid];
            float4 a0 = *(const float4*)&h1s[k][0];
            float4 a1 = *(const float4*)&h1s[k][4];
            float hv[ROWS] = {a0.x,a0.y,a0.z,a0.w,a1.x,a1.y,a1.z,a1.w};
            #pragma unroll
            for (int b = 0; b < ROWS; ++b) {
                ar[b] = fmaf(hv[b], w_r, ar[b]);
                az[b] = fmaf(hv[b], w_z, az[b]);
                ah[b] = fmaf(hv[b], w_n, ah[b]);
            }
        }
        #pragma unroll
        for (int k = 0; k < K1X; ++k) {                  // x-part -> r,z,in
            const float* wr = W1t + (size_t)(HID + k)*G3;
            float w_r = wr[tid], w_z = wr[HID + tid], w_n = wr[2*HID + tid];
            float4 a0 = *(const float4*)&xf[k][0];
            float4 a1 = *(const float4*)&xf[k][4];
            float xv[ROWS] = {a0.x,a0.y,a0.z,a0.w,a1.x,a1.y,a1.z,a1.w};
            #pragma unroll
            for (int b = 0; b < ROWS; ++b) {
                ar[b] = fmaf(xv[b], w_r, ar[b]);
                az[b] = fmaf(xv[b], w_z, az[b]);
                ai[b] = fmaf(xv[b], w_n, ai[b]);
            }
        }
        float4 p0 = *(const float4*)&h1s[tid][0];
        float4 p1 = *(const float4*)&h1s[tid][4];
        float h1old[ROWS] = {p0.x,p0.y,p0.z,p0.w,p1.x,p1.y,p1.z,p1.w};
        float h1n[ROWS];
        #pragma unroll
        for (int b = 0; b < ROWS; ++b) {
            float r  = sigmf(ar[b] + br1);
            float zg = sigmf(az[b] + bz1);
            float n  = tanhf(fmaf(r, ah[b] + bn1, ai[b] + bi1));
            h1n[b] = (1.0f - zg)*n + zg*h1old[b];
        }
        __syncthreads();   // everyone done reading old h1
        *(float4*)&h1s[tid][0] = make_float4(h1n[0],h1n[1],h1n[2],h1n[3]);
        *(float4*)&h1s[tid][4] = make_float4(h1n[4],h1n[5],h1n[6],h1n[7]);
        if (t == 0) {      // hx[1] = hx[0] at i==0
            *(float4*)&h2s[tid][0] = make_float4(h1n[0],h1n[1],h1n[2],h1n[3]);
            *(float4*)&h2s[tid][4] = make_float4(h1n[4],h1n[5],h1n[6],h1n[7]);
        }
        __syncthreads();

        // ---- GRU2: input = h1(new), hidden = h2 ----
        #pragma unroll
        for (int b = 0; b < ROWS; ++b) { ar[b]=0.f; az[b]=0.f; ai[b]=0.f; ah[b]=0.f; }
        #pragma unroll 4
        for (int k = 0; k < HID; ++k) {                  // h2-part -> r,z,hn
            const float* wr = W2t + (size_t)k*G3;
            float w_r = wr[tid], w_z = wr[HID + tid], w_n = wr[2*HID + tid];
            float4 a0 = *(const float4*)&h2s[k][0];
            float4 a1 = *(const float4*)&h2s[k][4];
            float hv[ROWS] = {a0.x,a0.y,a0.z,a0.w,a1.x,a1.y,a1.z,a1.w};
            #pragma unroll
            for (int b = 0; b < ROWS; ++b) {
                ar[b] = fmaf(hv[b], w_r, ar[b]);
                az[b] = fmaf(hv[b], w_z, az[b]);
                ah[b] = fmaf(hv[b], w_n, ah[b]);
            }
        }
        #pragma unroll 4
        for (int k = 0; k < HID; ++k) {                  // h1-part -> r,z,in
            const float* wr = W2t + (size_t)(HID + k)*G3;
            float w_r = wr[tid], w_z = wr[HID + tid], w_n = wr[2*HID + tid];
            float4 a0 = *(const float4*)&h1s[k][0];
            float4 a1 = *(const float4*)&h1s[k][4];
            float hv[ROWS] = {a0.x,a0.y,a0.z,a0.w,a1.x,a1.y,a1.z,a1.w};
            #pragma unroll
            for (int b = 0; b < ROWS; ++b) {
                ar[b] = fmaf(hv[b], w_r, ar[b]);
                az[b] = fmaf(hv[b], w_z, az[b]);
                ai[b] = fmaf(hv[b], w_n, ai[b]);
            }
        }
        float4 q0 = *(const float4*)&h2s[tid][0];
        float4 q1 = *(const float4*)&h2s[tid][4];
        float h2old[ROWS] = {q0.x,q0.y,q0.z,q0.w,q1.x,q1.y,q1.z,q1.w};
        float h2n[ROWS];
        #pragma unroll
        for (int b = 0; b < ROWS; ++b) {
            float r  = sigmf(ar[b] + br2);
            float zg = sigmf(az[b] + bz2);
            float n  = tanhf(fmaf(r, ah[b] + bn2, ai[b] + bi2));
            h2n[b] = (1.0f - zg)*n + zg*h2old[b];
        }
        __syncthreads();
        *(float4*)&h2s[tid][0] = make_float4(h2n[0],h2n[1],h2n[2],h2n[3]);
        *(float4*)&h2s[tid][4] = make_float4(h2n[4],h2n[5],h2n[6],h2n[7]);
        __syncthreads();

        // ---- note = tanh(h2) @ W_out^T + b_out; Bernoulli sample ----
        {
            float na[CH];
            #pragma unroll
            for (int c = 0; c < CH; ++c) na[c] = 0.0f;
            for (int kk = ln; kk < HID; kk += 64) {
                float th = tanhf(h2s[kk][wv]);
                #pragma unroll
                for (int c = 0; c < CH; ++c) na[c] = fmaf(th, wouts[kk][c], na[c]);
            }
            #pragma unroll
            for (int c = 0; c < CH; ++c) {
                #pragma unroll
                for (int off = 32; off; off >>= 1)
                    na[c] += __shfl_xor(na[c], off, 64);
            }
            if (ln < CH) {
                int c = ln;
                float note = na[c] + b_out[c];
                float sg = sigmf(note);
                float rv = rnd[((size_t)t*B_TOT + row0 + wv)*CH + c];
                xf[c][wv] = (sg - rv > 0.0f) ? 1.0f : 0.0f;   // feedback bit
                out[((size_t)(row0 + wv)*T_LEN + t)*CH + c] = note;
            }
        }
        __syncthreads();
    }
}

extern "C" void kernel_launch(void* const* d_in, const int* in_sizes, int n_in,
                              void* d_out, int out_size, void* d_ws, size_t ws_size,
                              hipStream_t stream)
{
    const float* z     = (const float*)d_in[0];
    const float* se    = (const float*)d_in[1];
    const float* skel  = (const float*)d_in[2];
    const float* cond  = (const float*)d_in[3];
    const float* rnd   = (const float*)d_in[4];
    const float* W_h   = (const float*)d_in[5];
    const float* b_h   = (const float*)d_in[6];
    const float* w_ih1 = (const float*)d_in[7];
    const float* w_hh1 = (const float*)d_in[8];
    const float* b_ih1 = (const float*)d_in[9];
    const float* b_hh1 = (const float*)d_in[10];
    const float* w_ih2 = (const float*)d_in[11];
    const float* w_hh2 = (const float*)d_in[12];
    const float* b_ih2 = (const float*)d_in[13];
    const float* b_hh2 = (const float*)d_in[14];
    const float* W_out = (const float*)d_in[15];
    const float* b_out = (const float*)d_in[16];
    float* ws  = (float*)d_ws;
    float* out = (float*)d_out;

    const int total = SZ_W1T + SZ_W2T + SZ_WHT;
    prep_kernel<<<(total + 255)/256, 256, 0, stream>>>(w_ih1, w_hh1, w_ih2, w_hh2, W_h, ws);
    note_decoder_kernel<<<NWG, NTHR, 0, stream>>>(z, se, skel, cond, rnd, b_h,
                                                  b_ih1, b_hh1, b_ih2, b_hh2,
                                                  W_out, b_out, ws, out);
}